// Round 6
// baseline (187.177 us; speedup 1.0000x reference)
//
#include <hip/hip_runtime.h>
#include <math.h>

// ---------------------------------------------------------------------------
// Encoder_Flows on MI355X — 6 dispatches.
// Row-locality: out[i] depends only on x[i] (+ agg for rows<1024).
//   prep  : proj1 (Y1^T = (flow[:1024]@wl1^T)^T, 32 blocks) + weight cvt.
//   tail  : rows [1024,32768) x ALL 4 LAYERS in one kernel (992 blocks);
//           x kept in LDS bf16 between layers; L2-4 use direct-fragment
//           MFMA (A from LDS, B from L2-resident weights, no k-loop barriers).
//   head_L: rows [0,1024): scan-GEMM agg (direct Y^T frags) + main GEMM +
//           normalize + FUSED next-layer proj (x in LDS -> YT_{L+1}).
// All GEMMs bf16 MFMA 16x16x32, fp32 accumulate. BM=32 per block.
// XOR-swizzled LDS (byte ^= (row&7)<<4) for conflict-free ds_read_b128.
// ---------------------------------------------------------------------------

typedef __attribute__((ext_vector_type(8))) short short8;
typedef __attribute__((ext_vector_type(4))) float f32x4;

constexpr int NROWS = 32768;
constexpr int KROWS = 1024;

static __device__ __forceinline__ unsigned short f2bf(float f) {
    unsigned int u = __float_as_uint(f);
    return (unsigned short)((u + 0x7fffu + ((u >> 16) & 1u)) >> 16);
}

// ---- reg-staging helpers (tile ROWS x 64 -> XOR-swizzled LDS) -------------
template<int ROWS>
struct RegsBF {
    short8 v[ROWS / 32];
    __device__ __forceinline__ void load(const unsigned short* src, int ld,
                                         int r0, int k0, int t) {
#pragma unroll
        for (int j = 0; j < ROWS / 32; ++j) {
            int idx = j * 256 + t; int r = idx >> 3, f = idx & 7;
            v[j] = *reinterpret_cast<const short8*>(
                src + (size_t)(r0 + r) * ld + k0 + f * 8);
        }
    }
    __device__ __forceinline__ void store(unsigned short* buf, int t) {
#pragma unroll
        for (int j = 0; j < ROWS / 32; ++j) {
            int idx = j * 256 + t; int r = idx >> 3, f = idx & 7;
            int off = (r * 128 + f * 16) ^ ((r & 7) << 4);
            *reinterpret_cast<short8*>((char*)buf + off) = v[j];
        }
    }
};

template<int ROWS>
struct RegsF32 {
    float4 v[ROWS / 16];
    __device__ __forceinline__ void load(const float* src, int ld,
                                         int r0, int k0, int t) {
#pragma unroll
        for (int j = 0; j < ROWS / 32; ++j) {
            int idx = j * 256 + t; int r = idx >> 3, f = idx & 7;
            const float* p = src + (size_t)(r0 + r) * ld + k0 + f * 8;
            v[2 * j]     = *reinterpret_cast<const float4*>(p);
            v[2 * j + 1] = *reinterpret_cast<const float4*>(p + 4);
        }
    }
    __device__ __forceinline__ void store(unsigned short* buf, int t) {
#pragma unroll
        for (int j = 0; j < ROWS / 32; ++j) {
            int idx = j * 256 + t; int r = idx >> 3, f = idx & 7;
            float4 a = v[2 * j], b = v[2 * j + 1];
            short8 s;
            s[0] = (short)f2bf(a.x); s[1] = (short)f2bf(a.y);
            s[2] = (short)f2bf(a.z); s[3] = (short)f2bf(a.w);
            s[4] = (short)f2bf(b.x); s[5] = (short)f2bf(b.y);
            s[6] = (short)f2bf(b.z); s[7] = (short)f2bf(b.w);
            int off = (r * 128 + f * 16) ^ ((r & 7) << 4);
            *reinterpret_cast<short8*>((char*)buf + off) = s;
        }
    }
};

// ---- L1-shape staged GEMM: DIN=1024, DOUT=128 (WN=2,WM=2,FM=1) ------------
template<bool BFP32>
__device__ __forceinline__ void gemm_l1(const float* __restrict__ X, int i0,
    const void* __restrict__ W, f32x4 (&acc)[1][4],
    unsigned short* Abuf, unsigned short* Bbuf, int t)
{
    const int wv = t >> 6, lane = t & 63, wr_ = wv >> 1, wc = wv & 1;
#pragma unroll
    for (int fj = 0; fj < 4; ++fj) acc[0][fj] = (f32x4){0.f, 0.f, 0.f, 0.f};
    RegsF32<32> ar; RegsBF<128> bb_; RegsF32<128> bf_;
    ar.load(X, 1024, i0, 0, t);
    if constexpr (BFP32) bf_.load((const float*)W, 1024, 0, 0, t);
    else                 bb_.load((const unsigned short*)W, 1024, 0, 0, t);
    for (int kt = 0; kt < 16; ++kt) {
        if (kt) __syncthreads();
        ar.store(Abuf, t);
        if constexpr (BFP32) bf_.store(Bbuf, t); else bb_.store(Bbuf, t);
        __syncthreads();
        if (kt + 1 < 16) {
            ar.load(X, 1024, i0, (kt + 1) * 64, t);
            if constexpr (BFP32) bf_.load((const float*)W, 1024, 0, (kt + 1) * 64, t);
            else                 bb_.load((const unsigned short*)W, 1024, 0, (kt + 1) * 64, t);
        }
#pragma unroll
        for (int kk = 0; kk < 2; ++kk) {
            const int rA = wr_ * 16 + (lane & 15);
            const int offA = (rA * 128 + kk * 64 + (lane >> 4) * 16) ^ ((rA & 7) << 4);
            short8 a = *reinterpret_cast<const short8*>((const char*)Abuf + offA);
            short8 b[4];
#pragma unroll
            for (int fj = 0; fj < 4; ++fj) {
                const int rB = wc * 64 + fj * 16 + (lane & 15);
                const int offB = (rB * 128 + kk * 64 + (lane >> 4) * 16) ^ ((rB & 7) << 4);
                b[fj] = *reinterpret_cast<const short8*>((const char*)Bbuf + offB);
            }
#pragma unroll
            for (int fj = 0; fj < 4; ++fj)
                acc[0][fj] = __builtin_amdgcn_mfma_f32_16x16x32_bf16(
                    a, b[fj], acc[0][fj], 0, 0, 0);
        }
    }
}

// ---- small GEMM, direct fragments (A: LDS-swizzled or global bf16) --------
template<int DIN, int DOUT, bool ALDS>
__device__ __forceinline__ void gemm_small(const void* __restrict__ Av,
    const unsigned short* __restrict__ W, f32x4 (&acc)[DOUT / 128][4], int t)
{
    constexpr int WN = DOUT / 64, WM = 4 / WN, FM = DOUT / 128;
    const int wv = t >> 6, lane = t & 63, wr_ = wv / WN, wc = wv % WN;
#pragma unroll
    for (int fi = 0; fi < FM; ++fi)
#pragma unroll
        for (int fj = 0; fj < 4; ++fj) acc[fi][fj] = (f32x4){0.f, 0.f, 0.f, 0.f};
#pragma unroll
    for (int kt = 0; kt < DIN / 32; ++kt) {
        const int k0 = kt * 32 + ((lane >> 4) << 3);
        short8 a[FM], b[4];
#pragma unroll
        for (int fi = 0; fi < FM; ++fi) {
            const int rA = wr_ * (32 / WM) + fi * 16 + (lane & 15);
            if constexpr (ALDS) {
                const int off = ((rA * DIN + k0) * 2) ^ ((rA & 7) << 4);
                a[fi] = *reinterpret_cast<const short8*>((const char*)Av + off);
            } else {
                a[fi] = *reinterpret_cast<const short8*>(
                    (const unsigned short*)Av + (size_t)rA * DIN + k0);
            }
        }
#pragma unroll
        for (int fj = 0; fj < 4; ++fj) {
            const int o = wc * 64 + fj * 16 + (lane & 15);
            b[fj] = *reinterpret_cast<const short8*>(W + (size_t)o * DIN + k0);
        }
#pragma unroll
        for (int fi = 0; fi < FM; ++fi)
#pragma unroll
            for (int fj = 0; fj < 4; ++fj)
                acc[fi][fj] = __builtin_amdgcn_mfma_f32_16x16x32_bf16(
                    a[fi], b[fj], acc[fi][fj], 0, 0, 0);
    }
}

// ---- scan-GEMM: agg = (L @ Y)/cnt from Y^T (DOUT x 1024), direct frags ----
template<int DOUT>
__device__ __forceinline__ void scan_agg(const unsigned short* __restrict__ YT,
    int i0, f32x4 (&agg)[DOUT / 128][4], int t)
{
    constexpr int WN = DOUT / 64, WM = 4 / WN, FM = DOUT / 128;
    const int wv = t >> 6, lane = t & 63, wr_ = wv / WN, wc = wv % WN;
#pragma unroll
    for (int fi = 0; fi < FM; ++fi)
#pragma unroll
        for (int fj = 0; fj < 4; ++fj) agg[fi][fj] = (f32x4){0.f, 0.f, 0.f, 0.f};
    const int nt = (i0 + 95) >> 6;              // ceil((i0+32)/64)
    for (int kt = 0; kt < nt; ++kt) {
#pragma unroll
        for (int kk = 0; kk < 2; ++kk) {
            const int jb = kt * 64 + kk * 32 + ((lane >> 4) << 3);
            short8 a[FM], b[4];
#pragma unroll
            for (int fi = 0; fi < FM; ++fi) {
                const int irow = i0 + wr_ * (32 / WM) + fi * 16 + (lane & 15);
#pragma unroll
                for (int e = 0; e < 8; ++e)
                    a[fi][e] = (short)((jb + e < irow) ? 0x3F80 : 0);
            }
#pragma unroll
            for (int fj = 0; fj < 4; ++fj) {
                const int o = wc * 64 + fj * 16 + (lane & 15);
                b[fj] = *reinterpret_cast<const short8*>(YT + (size_t)o * KROWS + jb);
            }
#pragma unroll
            for (int fi = 0; fi < FM; ++fi)
#pragma unroll
                for (int fj = 0; fj < 4; ++fj)
                    agg[fi][fj] = __builtin_amdgcn_mfma_f32_16x16x32_bf16(
                        a[fi], b[fj], agg[fi][fj], 0, 0, 0);
        }
    }
#pragma unroll
    for (int fi = 0; fi < FM; ++fi)
#pragma unroll
        for (int reg = 0; reg < 4; ++reg) {
            const int i_abs = i0 + wr_ * (32 / WM) + fi * 16 + ((lane >> 4) << 2) + reg;
            const float inv = 1.0f / (float)(i_abs > 1 ? i_abs : 1);
#pragma unroll
            for (int fj = 0; fj < 4; ++fj) agg[fi][fj][reg] *= inv;
        }
}

// ---- bias(+agg) add, row L2-norm across block -> inv scale ----------------
template<int DOUT>
__device__ __forceinline__ void norm_rows(f32x4 (&acc)[DOUT / 128][4],
    const float* __restrict__ bias, const f32x4 (*agg)[4],
    float* ssred, int t, float (&inv)[DOUT / 128][4])
{
    constexpr int WN = DOUT / 64, WM = 4 / WN, FM = DOUT / 128;
    const int wv = t >> 6, lane = t & 63, wr_ = wv / WN, wc = wv % WN;
    float bb[4];
#pragma unroll
    for (int fj = 0; fj < 4; ++fj) bb[fj] = bias[wc * 64 + fj * 16 + (lane & 15)];
#pragma unroll
    for (int fi = 0; fi < FM; ++fi)
#pragma unroll
        for (int fj = 0; fj < 4; ++fj)
#pragma unroll
            for (int reg = 0; reg < 4; ++reg) {
                float v = acc[fi][fj][reg] + bb[fj];
                if (agg) v += agg[fi][fj][reg];
                acc[fi][fj][reg] = v;
            }
#pragma unroll
    for (int fi = 0; fi < FM; ++fi)
#pragma unroll
        for (int reg = 0; reg < 4; ++reg) {
            float s = 0.f;
#pragma unroll
            for (int fj = 0; fj < 4; ++fj) { float v = acc[fi][fj][reg]; s += v * v; }
#pragma unroll
            for (int m = 8; m >= 1; m >>= 1) s += __shfl_xor(s, m);
            if ((lane & 15) == 0) {
                const int rl = wr_ * (32 / WM) + fi * 16 + ((lane >> 4) << 2) + reg;
                ssred[wc * 32 + rl] = s;
            }
        }
    __syncthreads();
#pragma unroll
    for (int fi = 0; fi < FM; ++fi)
#pragma unroll
        for (int reg = 0; reg < 4; ++reg) {
            const int rl = wr_ * (32 / WM) + fi * 16 + ((lane >> 4) << 2) + reg;
            float s = 0.f;
#pragma unroll
            for (int c = 0; c < WN; ++c) s += ssred[c * 32 + rl];
            inv[fi][reg] = 1.0f / fmaxf(sqrtf(s), 1e-12f);
        }
}

// ---- store normalized rows to LDS xbuf (bf16, swizzled, stride DOUT) ------
template<int DOUT>
__device__ __forceinline__ void storeX(const f32x4 (&acc)[DOUT / 128][4],
    const float (&inv)[DOUT / 128][4], unsigned short* xbuf, int t)
{
    constexpr int WN = DOUT / 64, WM = 4 / WN, FM = DOUT / 128;
    const int wv = t >> 6, lane = t & 63, wr_ = wv / WN, wc = wv % WN;
#pragma unroll
    for (int fi = 0; fi < FM; ++fi)
#pragma unroll
        for (int fj = 0; fj < 4; ++fj)
#pragma unroll
            for (int reg = 0; reg < 4; ++reg) {
                const int rl = wr_ * (32 / WM) + fi * 16 + ((lane >> 4) << 2) + reg;
                const int cl = wc * 64 + fj * 16 + (lane & 15);
                const int off = ((rl * DOUT + cl) * 2) ^ ((rl & 7) << 4);
                *reinterpret_cast<unsigned short*>((char*)xbuf + off) =
                    f2bf(acc[fi][fj][reg] * inv[fi][reg]);
            }
}

// ---------------------------------------------------------------------------
// prep: blocks [0,32) proj1 -> YT1; blocks [32,352) weight cvt; tuple scalar.
// ---------------------------------------------------------------------------
__global__ __launch_bounds__(256, 2)
void prep_kernel(const float* __restrict__ flow, const float* __restrict__ wl1,
                 const float* __restrict__ wr1, const float* __restrict__ wl2,
                 const float* __restrict__ wr2, const float* __restrict__ wl3,
                 const float* __restrict__ wr3, const float* __restrict__ wl4,
                 const float* __restrict__ wr4,
                 unsigned short* __restrict__ wbf,
                 unsigned short* __restrict__ YT1, float* __restrict__ outscalar)
{
    __shared__ unsigned short Abuf[32 * 64];
    __shared__ unsigned short Bbuf[128 * 64];
    const int t = threadIdx.x, bid = blockIdx.x;
    if (bid >= 32) {
        if (bid == 32 && t == 0) outscalar[0] = 1.0f;
        int g = (bid - 32) * 1024 + t * 4;
        const float* src; int off;
        if      (g < 131072) { src = wr1; off = g; }
        else if (g < 163840) { src = wl2; off = g - 131072; }
        else if (g < 196608) { src = wr2; off = g - 163840; }
        else if (g < 229376) { src = wl3; off = g - 196608; }
        else if (g < 262144) { src = wr3; off = g - 229376; }
        else if (g < 294912) { src = wl4; off = g - 262144; }
        else                 { src = wr4; off = g - 294912; }
        float4 v = *reinterpret_cast<const float4*>(src + off);
        ushort4 o4;
        o4.x = f2bf(v.x); o4.y = f2bf(v.y); o4.z = f2bf(v.z); o4.w = f2bf(v.w);
        *reinterpret_cast<ushort4*>(wbf + g) = o4;
        return;
    }
    const int i0 = bid * 32, wv = t >> 6, lane = t & 63;
    const int wr_ = wv >> 1, wc = wv & 1;
    f32x4 acc[1][4];
    gemm_l1<true>(flow, i0, wl1, acc, Abuf, Bbuf, t);
#pragma unroll
    for (int fj = 0; fj < 4; ++fj) {
        const int rl0 = wr_ * 16 + ((lane >> 4) << 2);
        const int cl  = wc * 64 + fj * 16 + (lane & 15);
        ushort4 y;
        y.x = f2bf(acc[0][fj][0]); y.y = f2bf(acc[0][fj][1]);
        y.z = f2bf(acc[0][fj][2]); y.w = f2bf(acc[0][fj][3]);
        *reinterpret_cast<ushort4*>(YT1 + (size_t)cl * KROWS + i0 + rl0) = y;
    }
}

// ---------------------------------------------------------------------------
// tail: rows [1024,32768), all 4 layers, one block = 32 rows.
// ---------------------------------------------------------------------------
__global__ __launch_bounds__(256, 4)
void tail_kernel(const float* __restrict__ flow,
    const unsigned short* __restrict__ wr1b, const float* __restrict__ bl1,
    const unsigned short* __restrict__ wr2b, const float* __restrict__ bl2,
    const unsigned short* __restrict__ wr3b, const float* __restrict__ bl3,
    const unsigned short* __restrict__ wr4b, const float* __restrict__ bl4,
    float* __restrict__ out)
{
    __shared__ unsigned short Abuf[32 * 64];
    __shared__ unsigned short Bbuf[128 * 64];
    __shared__ unsigned short xbuf[32 * 256];
    __shared__ float ssred[128];
    const int t = threadIdx.x, wv = t >> 6, lane = t & 63;
    const int i0 = KROWS + blockIdx.x * 32;

    // L1 (din=1024 -> 128)
    f32x4 acc1[1][4];
    gemm_l1<false>(flow, i0, wr1b, acc1, Abuf, Bbuf, t);
    float inv1[1][4];
    norm_rows<128>(acc1, bl1, nullptr, ssred, t, inv1);
    storeX<128>(acc1, inv1, xbuf, t);
    __syncthreads();
    // L2 (128 -> 256)
    f32x4 acc2[2][4];
    gemm_small<128, 256, true>(xbuf, wr2b, acc2, t);
    float inv2[2][4];
    norm_rows<256>(acc2, bl2, nullptr, ssred, t, inv2);
    storeX<256>(acc2, inv2, xbuf, t);
    __syncthreads();
    // L3 (256 -> 128)
    f32x4 acc3[1][4];
    gemm_small<256, 128, true>(xbuf, wr3b, acc3, t);
    float inv3[1][4];
    norm_rows<128>(acc3, bl3, nullptr, ssred, t, inv3);
    storeX<128>(acc3, inv3, xbuf, t);
    __syncthreads();
    // L4 (128 -> 256) + relu -> out
    f32x4 acc4[2][4];
    gemm_small<128, 256, true>(xbuf, wr4b, acc4, t);
    float inv4[2][4];
    norm_rows<256>(acc4, bl4, nullptr, ssred, t, inv4);
    {
        const int wr_ = 0, wc = wv;            // DOUT=256: WM=1, WN=4
        (void)wr_;
#pragma unroll
        for (int fi = 0; fi < 2; ++fi)
#pragma unroll
            for (int fj = 0; fj < 4; ++fj)
#pragma unroll
                for (int reg = 0; reg < 4; ++reg) {
                    const int rl = fi * 16 + ((lane >> 4) << 2) + reg;
                    const int cl = wc * 64 + fj * 16 + (lane & 15);
                    float v = acc4[fi][fj][reg] * inv4[fi][reg];
                    v = fmaxf(v, 0.f);
                    out[(size_t)(i0 + rl) * 256 + cl] = v;
                }
    }
}

// ---------------------------------------------------------------------------
// head_L: rows [0,1024): scan-agg + main GEMM + normalize (+relu L4)
//         + fused next-layer proj (YTnext) via xbuf.
// ---------------------------------------------------------------------------
template<int DIN, int DOUT, int DNEXT, bool AFP32, bool RELU>
__global__ __launch_bounds__(256, 2)
void head_kernel(const void* __restrict__ Xv,
    const unsigned short* __restrict__ W, const float* __restrict__ bias,
    const unsigned short* __restrict__ YT,
    const unsigned short* __restrict__ Wnext,
    unsigned short* __restrict__ xdst, float* __restrict__ outf,
    unsigned short* __restrict__ YTnext)
{
    constexpr int WN = DOUT / 64, WM = 4 / WN, FM = DOUT / 128;
    __shared__ unsigned short Abuf[32 * 64];
    __shared__ unsigned short Bbuf[128 * 64];
    __shared__ unsigned short xbuf[32 * 256];
    __shared__ float ssred[128];
    const int t = threadIdx.x, wv = t >> 6, lane = t & 63;
    const int wr_ = wv / WN, wc = wv % WN;
    const int i0 = blockIdx.x * 32;

    f32x4 agg[FM][4];
    scan_agg<DOUT>(YT, i0, agg, t);

    f32x4 acc[FM][4];
    if constexpr (AFP32)
        gemm_l1<false>((const float*)Xv, i0, W, acc, Abuf, Bbuf, t);
    else
        gemm_small<DIN, DOUT, false>(
            (const unsigned short*)Xv + (size_t)i0 * DIN, W, acc, t);

    float inv[FM][4];
    norm_rows<DOUT>(acc, bias, &agg[0], ssred, t, inv);

#pragma unroll
    for (int fi = 0; fi < FM; ++fi)
#pragma unroll
        for (int fj = 0; fj < 4; ++fj)
#pragma unroll
            for (int reg = 0; reg < 4; ++reg) {
                const int rl = wr_ * (32 / WM) + fi * 16 + ((lane >> 4) << 2) + reg;
                const int cl = wc * 64 + fj * 16 + (lane & 15);
                float v = acc[fi][fj][reg] * inv[fi][reg];
                if constexpr (RELU) {
                    v = fmaxf(v, 0.f);
                    outf[(size_t)(i0 + rl) * 256 + cl] = v;
                } else {
                    const unsigned short u = f2bf(v);
                    xdst[(size_t)(i0 + rl) * DOUT + cl] = u;
                    const int off = ((rl * DOUT + cl) * 2) ^ ((rl & 7) << 4);
                    *reinterpret_cast<unsigned short*>((char*)xbuf + off) = u;
                }
            }

    if constexpr (DNEXT > 0) {
        __syncthreads();
        f32x4 acc2[DNEXT / 128][4];
        gemm_small<DOUT, DNEXT, true>(xbuf, Wnext, acc2, t);
        constexpr int WN2 = DNEXT / 64, WM2 = 4 / WN2, FM2 = DNEXT / 128;
        const int wr2 = wv / WN2, wc2 = wv % WN2;
#pragma unroll
        for (int fi = 0; fi < FM2; ++fi)
#pragma unroll
            for (int fj = 0; fj < 4; ++fj) {
                const int rl0 = wr2 * (32 / WM2) + fi * 16 + ((lane >> 4) << 2);
                const int cl  = wc2 * 64 + fj * 16 + (lane & 15);
                ushort4 y;
                y.x = f2bf(acc2[fi][fj][0]); y.y = f2bf(acc2[fi][fj][1]);
                y.z = f2bf(acc2[fi][fj][2]); y.w = f2bf(acc2[fi][fj][3]);
                *reinterpret_cast<ushort4*>(YTnext + (size_t)cl * KROWS + i0 + rl0) = y;
            }
    }
}

extern "C" void kernel_launch(void* const* d_in, const int* in_sizes, int n_in,
                              void* d_out, int out_size, void* d_ws, size_t ws_size,
                              hipStream_t stream)
{
    const float* flow = (const float*)d_in[0];
    const float* wl1 = (const float*)d_in[1];
    const float* bl1 = (const float*)d_in[2];
    const float* wr1 = (const float*)d_in[3];
    const float* wl2 = (const float*)d_in[4];
    const float* bl2 = (const float*)d_in[5];
    const float* wr2 = (const float*)d_in[6];
    const float* wl3 = (const float*)d_in[7];
    const float* bl3 = (const float*)d_in[8];
    const float* wr3 = (const float*)d_in[9];
    const float* wl4 = (const float*)d_in[10];
    const float* bl4 = (const float*)d_in[11];
    const float* wr4 = (const float*)d_in[12];
    float* out = (float*)d_out;

    char* p = (char*)d_ws;
    unsigned short* wbf = (unsigned short*)p;  p += 1 << 20;     // 327680 bf16 used
    unsigned short* YT1 = (unsigned short*)p;  p += (size_t)128 * KROWS * 2;
    unsigned short* YT2 = (unsigned short*)p;  p += (size_t)256 * KROWS * 2;
    unsigned short* YT3 = (unsigned short*)p;  p += (size_t)128 * KROWS * 2;
    unsigned short* YT4 = (unsigned short*)p;  p += (size_t)256 * KROWS * 2;
    unsigned short* x1h = (unsigned short*)p;  p += (size_t)KROWS * 128 * 2;
    unsigned short* x2h = (unsigned short*)p;  p += (size_t)KROWS * 256 * 2;
    unsigned short* x3h = (unsigned short*)p;

    const unsigned short* wr1b = wbf;
    const unsigned short* wl2b = wbf + 131072;
    const unsigned short* wr2b = wbf + 163840;
    const unsigned short* wl3b = wbf + 196608;
    const unsigned short* wr3b = wbf + 229376;
    const unsigned short* wl4b = wbf + 262144;
    const unsigned short* wr4b = wbf + 294912;

    // D1: proj1 + weight cvt (+ tuple scalar)
    prep_kernel<<<352, 256, 0, stream>>>(flow, wl1, wr1, wl2, wr2, wl3, wr3,
                                         wl4, wr4, wbf, YT1,
                                         out + (size_t)NROWS * 256);
    // D2: tail — rows [1024,32768), all 4 layers
    tail_kernel<<<992, 256, 0, stream>>>(flow, wr1b, bl1, wr2b, bl2,
                                         wr3b, bl3, wr4b, bl4, out);
    // D3-D6: heads — rows [0,1024), one fused kernel per layer
    head_kernel<1024, 128, 256, true , false><<<32, 256, 0, stream>>>(
        flow, wr1b, bl1, YT1, wl2b, x1h, nullptr, YT2);
    head_kernel< 128, 256, 128, false, false><<<32, 256, 0, stream>>>(
        x1h, wr2b, bl2, YT2, wl3b, x2h, nullptr, YT3);
    head_kernel< 256, 128, 256, false, false><<<32, 256, 0, stream>>>(
        x2h, wr3b, bl3, YT3, wl4b, x3h, nullptr, YT4);
    head_kernel< 128, 256,   0, false, true ><<<32, 256, 0, stream>>>(
        x3h, wr4b, bl4, YT4, nullptr, nullptr, out, nullptr);
}